// Round 3
// baseline (193.680 us; speedup 1.0000x reference)
//
#include <hip/hip_runtime.h>

// StyleConv3D implicit-GEMM on bf16 MFMA (gfx950).
// B=8, Cin=32, Cout=32, D=48, K=3, VALID -> Dout=46.
// GEMM per batch: Y[cout=32][N=spatial] = W[32 x 864] * X[864 x N]
// K order: chunk(2 x 16ci) -> tap(27->28) x ci16.
// R3: T14 stage-split (issue chunk-1 loads before chunk-0 compute),
//     native bf16 convert, A-frag distance-1 prefetch.

typedef unsigned short u16;
typedef __bf16 bf16x8 __attribute__((ext_vector_type(8)));
typedef u16 u16x8 __attribute__((ext_vector_type(8)));
typedef float f32x4 __attribute__((ext_vector_type(4)));

__device__ __forceinline__ u16 f2bf(float f) {
    __bf16 h = (__bf16)f;
    return __builtin_bit_cast(u16, h);
}

// ---------------- Kernel A: modulate + demodulate -> bf16 A-layout --------
__global__ __launch_bounds__(64) void wnorm_kernel(
    const float* __restrict__ s,   // (8,2)
    const float* __restrict__ sw,  // (32,2)
    const float* __restrict__ sb,  // (32,)
    const float* __restrict__ w,   // (32,32,27)
    u16* __restrict__ wA)          // [b][chunk][cout][tap28][ci16]
{
    int bc = blockIdx.x;
    int b = bc >> 5, co = bc & 31;
    int lane = threadIdx.x;

    float s0 = s[2 * b], s1 = s[2 * b + 1];

    float sum = 0.f;
    for (int i = lane; i < 864; i += 64) {
        int ci = i / 27;
        float m = fmaf(s0, sw[2 * ci], fmaf(s1, sw[2 * ci + 1], sb[ci]));
        float v = w[co * 864 + i] * m;
        sum += v * v;
    }
#pragma unroll
    for (int off = 32; off; off >>= 1) sum += __shfl_xor(sum, off, 64);
    float rn = 1.0f / sqrtf(sum + 1e-8f);

    for (int i = lane; i < 864; i += 64) {
        int ci = i / 27, tap = i - ci * 27;
        float m = fmaf(s0, sw[2 * ci], fmaf(s1, sw[2 * ci + 1], sb[ci]));
        float v = w[co * 864 + i] * m * rn;
        int chunk = ci >> 4, ci16 = ci & 15;
        wA[(((b * 2 + chunk) * 32 + co) * 28 + tap) * 16 + ci16] = f2bf(v);
    }
    if (lane < 32) {
        int c = lane >> 4, ci16 = lane & 15;
        wA[(((b * 2 + c) * 32 + co) * 28 + 27) * 16 + ci16] = 0;
    }
}

// ---------------- Kernel B: implicit-GEMM conv ----------------------------
struct Site { int off; int cgrp; bool inb; };
__device__ __forceinline__ Site site_of(int idx, int z0, int y0) {
    Site st;
    int x = idx % 50; int r = idx / 50;
    st.cgrp = r & 1; r >>= 1;
    int y = r % 6, z = r / 6;
    int gz = z0 + z, gy = y0 + y;
    st.inb = (x < 48) && (gy < 48) && (gz < 48);
    int cx = x < 48 ? x : 47;
    int cy = gy < 48 ? gy : 47;
    int cz = gz < 48 ? gz : 47;
    st.off = cz * 2304 + cy * 48 + cx;
    return st;
}

#define LOAD_K(kk, chunk) { \
    Site st = site_of(t + (kk) * 512, z0, y0); \
    const float* xp = xin + (size_t)(b * 32 + (chunk) * 16 + st.cgrp * 8) * 110592 + st.off; \
    _Pragma("unroll") for (int j = 0; j < 8; ++j) g[kk][j] = xp[(size_t)j * 110592]; }

#define LOAD_TAIL(chunk) if (t < 16) { \
    Site st = site_of(3584 + t, z0, y0); \
    const float* xp = xin + (size_t)(b * 32 + (chunk) * 16 + st.cgrp * 8) * 110592 + st.off; \
    _Pragma("unroll") for (int j = 0; j < 8; ++j) gt[j] = xp[(size_t)j * 110592]; }

#define CONV_K(kk) { \
    Site st = site_of(t + (kk) * 512, z0, y0); \
    u16x8 v; \
    _Pragma("unroll") for (int j = 0; j < 8; ++j) v[j] = f2bf(st.inb ? g[kk][j] : 0.f); \
    cv[kk] = v; }

#define CONV_TAIL() if (t < 16) { \
    Site st = site_of(3584 + t, z0, y0); \
    u16x8 v; \
    _Pragma("unroll") for (int j = 0; j < 8; ++j) v[j] = f2bf(st.inb ? gt[j] : 0.f); \
    cvt_tail = v; }

#define WRITE_K(kk) *(u16x8*)&sx[(t + (kk) * 512) * 8] = cv[kk];
#define WRITE_TAIL() if (t < 16) { *(u16x8*)&sx[(3584 + t) * 8] = cvt_tail; }

#define COMPUTE_RANGE(chunk, S0, S1) { \
    const u16* wAc = wA + ((b * 2) + (chunk)) * (32 * 28 * 16); \
    u16x8 cA0 = *(const u16x8*)(wAc + aoff + (S0) * 32); \
    u16x8 cA1 = *(const u16x8*)(wAc + aoff + 16 * 28 * 16 + (S0) * 32); \
    _Pragma("unroll") \
    for (int s = (S0); s < (S1); ++s) { \
        u16x8 nA0 = cA0, nA1 = cA1; \
        if (s + 1 < 14) { \
            nA0 = *(const u16x8*)(wAc + aoff + (s + 1) * 32); \
            nA1 = *(const u16x8*)(wAc + aoff + 16 * 28 * 16 + (s + 1) * 32); \
        } \
        int tapA = 2 * s + tp; \
        int tapB = tapA > 26 ? 26 : tapA; \
        int dz = tapB / 9; \
        int rr = tapB - dz * 9; \
        int dy = rr / 3; \
        int dx = rr - dy * 3; \
        int zr = zw + dz; \
        _Pragma("unroll") \
        for (int yr = 0; yr < 2; ++yr) { \
            int yy = 2 * yp + yr + dy; \
            int eb = (((zr * 6 + yy) * 2 + ch) * 50 + ln + dx) * 8; \
            _Pragma("unroll") \
            for (int xt = 0; xt < 3; ++xt) { \
                bf16x8 Bf = __builtin_bit_cast(bf16x8, *(const u16x8*)&sx[eb + xt * 128]); \
                acc[yr][xt][0] = __builtin_amdgcn_mfma_f32_16x16x32_bf16( \
                    __builtin_bit_cast(bf16x8, cA0), Bf, acc[yr][xt][0], 0, 0, 0); \
                acc[yr][xt][1] = __builtin_amdgcn_mfma_f32_16x16x32_bf16( \
                    __builtin_bit_cast(bf16x8, cA1), Bf, acc[yr][xt][1], 0, 0, 0); \
            } \
        } \
        cA0 = nA0; cA1 = nA1; \
    } }

__global__ __launch_bounds__(512, 4) void conv_mfma(
    const float* __restrict__ xin,   // (8,32,48,48,48) f32
    const u16* __restrict__ wA,
    const float* __restrict__ bias,  // (32,)
    float* __restrict__ out)         // (8,32,46,46,46) f32
{
    __shared__ u16 sx[28800];   // [z6][y6][ch2][x50][ci8] bf16

    int blk = blockIdx.x;
    int zt = blk % 12, yt = (blk / 12) % 12, b = blk / 144;
    int z0 = zt * 4, y0 = yt * 4;

    int t = threadIdx.x;
    int l = t & 63, w = t >> 6;
    int ln = l & 15;            // MFMA col (x within 16-tile)
    int ch = (l >> 4) & 1;      // ci half
    int tp = l >> 5;            // tap parity
    int rg = l >> 4;            // C-layout row group
    int zw = w & 3, yp = w >> 2;

    int aoff = (ln * 28 + tp) * 16 + ch * 8;

    float g[7][8];
    float gt[8];
    u16x8 cv[7];
    u16x8 cvt_tail;

    f32x4 acc[2][3][2];
#pragma unroll
    for (int i = 0; i < 2; i++)
#pragma unroll
        for (int j = 0; j < 3; j++)
#pragma unroll
            for (int h = 0; h < 2; h++) acc[i][j][h] = (f32x4)0.f;

    // ---- phase 0: stage chunk 0 (nothing to overlap with) ----
    LOAD_K(0, 0) LOAD_K(1, 0) LOAD_K(2, 0) LOAD_K(3, 0)
    LOAD_K(4, 0) LOAD_K(5, 0) LOAD_K(6, 0) LOAD_TAIL(0)
    CONV_K(0) CONV_K(1) CONV_K(2) CONV_K(3)
    CONV_K(4) CONV_K(5) CONV_K(6) CONV_TAIL()
    WRITE_K(0) WRITE_K(1) WRITE_K(2) WRITE_K(3)
    WRITE_K(4) WRITE_K(5) WRITE_K(6) WRITE_TAIL()
    __syncthreads();

    // ---- phase 1: compute chunk 0 while staging chunk 1 into regs ----
    LOAD_K(0, 1) LOAD_K(1, 1) LOAD_K(2, 1) LOAD_K(3, 1)
    COMPUTE_RANGE(0, 0, 7)
    CONV_K(0) CONV_K(1) CONV_K(2) CONV_K(3)
    LOAD_K(4, 1) LOAD_K(5, 1) LOAD_K(6, 1) LOAD_TAIL(1)
    COMPUTE_RANGE(0, 7, 14)
    __syncthreads();            // all waves done reading chunk-0 LDS
    CONV_K(4) CONV_K(5) CONV_K(6) CONV_TAIL()
    WRITE_K(0) WRITE_K(1) WRITE_K(2) WRITE_K(3)
    WRITE_K(4) WRITE_K(5) WRITE_K(6) WRITE_TAIL()
    __syncthreads();
    COMPUTE_RANGE(1, 0, 14)

    // ---- store ----
    int oz = z0 + zw;
    if (oz < 46) {
#pragma unroll
        for (int yr = 0; yr < 2; ++yr) {
            int oy = y0 + 2 * yp + yr;
            if (oy >= 46) continue;
#pragma unroll
            for (int xt = 0; xt < 3; ++xt) {
                int ox = xt * 16 + ln;
                if (ox >= 46) continue;
#pragma unroll
                for (int h = 0; h < 2; ++h) {
                    f32x4 a = acc[yr][xt][h];
#pragma unroll
                    for (int r = 0; r < 4; ++r) {
                        int co = h * 16 + rg * 4 + r;
                        out[(size_t)(b * 32 + co) * 97336 + oz * 2116 + oy * 46 + ox]
                            = a[r] + bias[co];
                    }
                }
            }
        }
    }
}

extern "C" void kernel_launch(void* const* d_in, const int* in_sizes, int n_in,
                              void* d_out, int out_size, void* d_ws, size_t ws_size,
                              hipStream_t stream) {
    const float* x    = (const float*)d_in[0];
    const float* s    = (const float*)d_in[1];
    const float* sw   = (const float*)d_in[2];
    const float* sb   = (const float*)d_in[3];
    const float* wgt  = (const float*)d_in[4];
    const float* bias = (const float*)d_in[5];
    float* out = (float*)d_out;
    u16* wA = (u16*)d_ws;

    hipLaunchKernelGGL(wnorm_kernel, dim3(256), dim3(64), 0, stream,
                       s, sw, sb, wgt, wA);
    hipLaunchKernelGGL(conv_mfma, dim3(12 * 12 * 8), dim3(512), 0, stream,
                       x, wA, bias, out);
}

// Round 4
// 112.731 us; speedup vs baseline: 1.7181x; 1.7181x over previous
//
#include <hip/hip_runtime.h>

// StyleConv3D implicit-GEMM on bf16 MFMA (gfx950).
// B=8, Cin=32, Cout=32, D=48, K=3, VALID -> Dout=46.
// R4: pre-pass x -> bf16 xT[b][c4][z][y][x][ci8]; conv stages via
// global_load_lds (16B DMA, no regs/VALU), 4 ci8-chunks double-buffered,
// DMA(c+1) issued before compute(c). Fallback to R2 path if ws too small.

typedef unsigned short u16;
typedef __bf16 bf16x8 __attribute__((ext_vector_type(8)));
typedef u16 u16x8 __attribute__((ext_vector_type(8)));
typedef float f32x4 __attribute__((ext_vector_type(4)));

#define CHUNKB   (110592 * 16)        // bytes per (b,c) chunk of xT
#define XT_BYTES (32u * CHUNKB)       // 56,623,104
#define WA_ELEMS (8 * 4 * 32 * 28 * 8)

__device__ __forceinline__ u16 f2bf(float f) {
    __bf16 h = (__bf16)f;
    return __builtin_bit_cast(u16, h);
}

__device__ __forceinline__ void dma16(const void* g, void* l) {
    __builtin_amdgcn_global_load_lds(
        (const __attribute__((address_space(1))) unsigned*)g,
        (__attribute__((address_space(3))) unsigned*)l, 16, 0, 0);
}

// ---------------- pre-pass: x f32 -> xT bf16 [bc][site][ci8] -------------
__global__ __launch_bounds__(256) void xpose_kernel(
    const float* __restrict__ x, u16* __restrict__ xT)
{
    int gid = blockIdx.x * 256 + threadIdx.x;    // 884,736 threads
    int quad = gid % 27648;
    int bc   = gid / 27648;                      // b*4 + c
    int site0 = quad * 4;
    const float* xp = x + (size_t)bc * 8 * 110592 + site0;
    float4 v[8];
#pragma unroll
    for (int j = 0; j < 8; ++j) v[j] = *(const float4*)(xp + (size_t)j * 110592);
    u16* op = xT + (size_t)gid * 32;
#pragma unroll
    for (int k = 0; k < 4; ++k) {
        u16x8 o;
#pragma unroll
        for (int j = 0; j < 8; ++j) o[j] = f2bf(((const float*)&v[j])[k]);
        *(u16x8*)(op + k * 8) = o;
    }
}

// ---------------- wnorm (main): wA[b][c4][cout][tap28][ci8] --------------
__global__ __launch_bounds__(64) void wnorm8_kernel(
    const float* __restrict__ s, const float* __restrict__ sw,
    const float* __restrict__ sb, const float* __restrict__ w,
    u16* __restrict__ wA)
{
    int bc = blockIdx.x;
    int b = bc >> 5, co = bc & 31;
    int lane = threadIdx.x;
    float s0 = s[2 * b], s1 = s[2 * b + 1];

    float sum = 0.f;
    for (int i = lane; i < 864; i += 64) {
        int ci = i / 27;
        float m = fmaf(s0, sw[2 * ci], fmaf(s1, sw[2 * ci + 1], sb[ci]));
        float v = w[co * 864 + i] * m;
        sum += v * v;
    }
#pragma unroll
    for (int off = 32; off; off >>= 1) sum += __shfl_xor(sum, off, 64);
    float rn = 1.0f / sqrtf(sum + 1e-8f);

    for (int i = lane; i < 864; i += 64) {
        int ci = i / 27, tap = i - ci * 27;
        float m = fmaf(s0, sw[2 * ci], fmaf(s1, sw[2 * ci + 1], sb[ci]));
        float v = w[co * 864 + i] * m * rn;
        int chunk = ci >> 3, ci8 = ci & 7;
        wA[(((b * 4 + chunk) * 32 + co) * 28 + tap) * 8 + ci8] = f2bf(v);
    }
    if (lane < 32) {
        int c = lane >> 3, ci8 = lane & 7;
        wA[(((b * 4 + c) * 32 + co) * 28 + 27) * 8 + ci8] = 0;
    }
}

// ---------------- conv (main): DMA-staged implicit GEMM ------------------
// Block: (b, zt, yt) -> outputs z0..z0+3, y0..y0+3, x 0..47 (masked >=46).
// LDS: 2 bufs x 2048 sites x 8ci bf16 = 2 x 32 KiB. Tile sites [z6][y6][x50]
// (site = z*300+y*50+x), padded to 2048 sites for uniform DMA issue count.
__global__ __launch_bounds__(512, 4) void conv_dma(
    const u16* __restrict__ xT, const u16* __restrict__ wA,
    const float* __restrict__ bias, float* __restrict__ out)
{
    __shared__ u16 sx[2][16384];

    int blk = blockIdx.x;
    int zt = blk % 12, yt = (blk / 12) % 12, b = blk / 144;
    int z0 = zt * 4, y0 = yt * 4;

    int t = threadIdx.x;
    int l = t & 63, w = t >> 6;
    int ln = l & 15;            // MFMA col (x within 16-tile) / A cout row
    int tq = l >> 4;            // k-octet: tap = 4s + tq
    int zw = w & 3, yp = w >> 2;

    // ---- per-thread DMA source offsets (4 sites), clamped in-chunk ----
    size_t goff[4];
#pragma unroll
    for (int i = 0; i < 4; ++i) {
        int sidx = t + i * 512;                  // 0..2047
        int z = sidx / 300, r = sidx - z * 300;
        int y = r / 50, x = r - y * 50;
        long o = ((long)((z0 + z) * 48 + (y0 + y)) * 48 + x) * 16;
        long mx = (long)CHUNKB - 16;
        goff[i] = (size_t)(o < mx ? o : mx);
    }

    // ---- per-thread B-read base per k-step (bytes into a buf) ----
    int bbase[7];
#pragma unroll
    for (int s = 0; s < 7; ++s) {
        int tap = 4 * s + tq; if (tap > 26) tap = 26;   // pad tap: A is 0
        int dz = tap / 9, rr = tap - dz * 9;
        int dy = rr / 3, dx = rr - dy * 3;
        bbase[s] = ((zw + dz) * 300 + (2 * yp + dy) * 50 + ln + dx) * 16;
    }
    int aoff = (ln * 28 + tq) * 16;   // bytes; +64/step, +7168 for cout half 1

    f32x4 acc[2][3][2];
#pragma unroll
    for (int i = 0; i < 2; i++)
#pragma unroll
        for (int j = 0; j < 3; j++)
#pragma unroll
            for (int h = 0; h < 2; h++) acc[i][j][h] = (f32x4)0.f;

    const char* xc = (const char*)xT + (size_t)(b * 4) * CHUNKB;

#define ISSUE(c, d) { \
    _Pragma("unroll") \
    for (int i = 0; i < 4; ++i) \
        dma16(xc + (size_t)(c) * CHUNKB + goff[i], \
              (char*)&sx[d][0] + (size_t)(i * 512 + w * 64) * 16); }

#define COMPUTE(c, d) { \
    const char* wB = (const char*)(wA + (size_t)(b * 4 + (c)) * (32 * 28 * 8)); \
    const char* sb_ = (const char*)&sx[d][0]; \
    u16x8 A0 = *(const u16x8*)(wB + aoff); \
    u16x8 A1 = *(const u16x8*)(wB + aoff + 7168); \
    _Pragma("unroll") \
    for (int s = 0; s < 7; ++s) { \
        u16x8 nA0 = A0, nA1 = A1; \
        if (s < 6) { \
            nA0 = *(const u16x8*)(wB + aoff + (s + 1) * 64); \
            nA1 = *(const u16x8*)(wB + aoff + 7168 + (s + 1) * 64); \
        } \
        _Pragma("unroll") \
        for (int yr = 0; yr < 2; ++yr) { \
            const char* p = sb_ + bbase[s] + yr * 800; \
            _Pragma("unroll") \
            for (int xt = 0; xt < 3; ++xt) { \
                bf16x8 Bf = *(const bf16x8*)(p + xt * 256); \
                acc[yr][xt][0] = __builtin_amdgcn_mfma_f32_16x16x32_bf16( \
                    __builtin_bit_cast(bf16x8, A0), Bf, acc[yr][xt][0], 0, 0, 0); \
                acc[yr][xt][1] = __builtin_amdgcn_mfma_f32_16x16x32_bf16( \
                    __builtin_bit_cast(bf16x8, A1), Bf, acc[yr][xt][1], 0, 0, 0); \
            } \
        } \
        A0 = nA0; A1 = nA1; \
    } }

    ISSUE(0, 0)
    __syncthreads();          // drains vmcnt -> chunk 0 in LDS
    ISSUE(1, 1)
    COMPUTE(0, 0)
    __syncthreads();          // chunk 1 landed; buf0 free
    ISSUE(2, 0)
    COMPUTE(1, 1)
    __syncthreads();
    ISSUE(3, 1)
    COMPUTE(2, 0)
    __syncthreads();
    COMPUTE(3, 1)

    // ---- store: C layout col=lane&15 (x), row=(lane>>4)*4+reg (cout) ----
    int oz = z0 + zw;
    if (oz < 46) {
#pragma unroll
        for (int yr = 0; yr < 2; ++yr) {
            int oy = y0 + 2 * yp + yr;
            if (oy >= 46) continue;
#pragma unroll
            for (int xt = 0; xt < 3; ++xt) {
                int ox = xt * 16 + ln;
                if (ox >= 46) continue;
#pragma unroll
                for (int h = 0; h < 2; ++h) {
                    f32x4 a = acc[yr][xt][h];
#pragma unroll
                    for (int r = 0; r < 4; ++r) {
                        int co = h * 16 + tq * 4 + r;
                        out[(size_t)(b * 32 + co) * 97336 + oz * 2116 + oy * 46 + ox]
                            = a[r] + bias[co];
                    }
                }
            }
        }
    }
#undef ISSUE
#undef COMPUTE
}

// ================= fallback path (R2, proven) ============================
__global__ __launch_bounds__(64) void wnorm16_kernel(
    const float* __restrict__ s, const float* __restrict__ sw,
    const float* __restrict__ sb, const float* __restrict__ w,
    u16* __restrict__ wA)          // [b][chunk2][cout][tap28][ci16]
{
    int bc = blockIdx.x;
    int b = bc >> 5, co = bc & 31;
    int lane = threadIdx.x;
    float s0 = s[2 * b], s1 = s[2 * b + 1];

    float sum = 0.f;
    for (int i = lane; i < 864; i += 64) {
        int ci = i / 27;
        float m = fmaf(s0, sw[2 * ci], fmaf(s1, sw[2 * ci + 1], sb[ci]));
        float v = w[co * 864 + i] * m;
        sum += v * v;
    }
#pragma unroll
    for (int off = 32; off; off >>= 1) sum += __shfl_xor(sum, off, 64);
    float rn = 1.0f / sqrtf(sum + 1e-8f);

    for (int i = lane; i < 864; i += 64) {
        int ci = i / 27, tap = i - ci * 27;
        float m = fmaf(s0, sw[2 * ci], fmaf(s1, sw[2 * ci + 1], sb[ci]));
        float v = w[co * 864 + i] * m * rn;
        int chunk = ci >> 4, ci16 = ci & 15;
        wA[(((b * 2 + chunk) * 32 + co) * 28 + tap) * 16 + ci16] = f2bf(v);
    }
    if (lane < 32) {
        int c = lane >> 4, ci16 = lane & 15;
        wA[(((b * 2 + c) * 32 + co) * 28 + 27) * 16 + ci16] = 0;
    }
}

__global__ __launch_bounds__(512) void conv_fallback(
    const float* __restrict__ xin, const u16* __restrict__ wA,
    const float* __restrict__ bias, float* __restrict__ out)
{
    __shared__ u16 sx[28800];

    int blk = blockIdx.x;
    int zt = blk % 12, yt = (blk / 12) % 12, b = blk / 144;
    int z0 = zt * 4, y0 = yt * 4;

    int t = threadIdx.x;
    int l = t & 63, w = t >> 6;
    int ln = l & 15, ch = (l >> 4) & 1, tp = l >> 5, rg = l >> 4;
    int zw = w & 3, yp = w >> 2;

    f32x4 acc[2][3][2];
#pragma unroll
    for (int i = 0; i < 2; i++)
#pragma unroll
        for (int j = 0; j < 3; j++)
#pragma unroll
            for (int h = 0; h < 2; h++) acc[i][j][h] = (f32x4)0.f;

    for (int chunk = 0; chunk < 2; ++chunk) {
        __syncthreads();
        for (int idx = t; idx < 3600; idx += 512) {
            int x = idx % 50;
            int r = idx / 50;
            int cg = r & 1; r >>= 1;
            int y = r % 6, z = r / 6;
            int gz = z0 + z, gy = y0 + y;
            bool inb = (x < 48) && (gy < 48) && (gz < 48);
            const float* xp = xin + (size_t)(b * 32 + chunk * 16 + cg * 8) * 110592
                              + gz * 2304 + gy * 48 + x;
            u16x8 v;
#pragma unroll
            for (int j = 0; j < 8; j++) {
                float f = inb ? xp[(size_t)j * 110592] : 0.f;
                v[j] = f2bf(f);
            }
            *(u16x8*)&sx[idx * 8] = v;
        }
        __syncthreads();

        const u16* wAc = wA + (b * 2 + chunk) * (32 * 28 * 16);
        int aoff = (ln * 28 + tp) * 16 + ch * 8;

#pragma unroll
        for (int s = 0; s < 14; ++s) {
            int tapA = 2 * s + tp;
            bf16x8 A0 = __builtin_bit_cast(bf16x8, *(const u16x8*)(wAc + aoff + s * 32));
            bf16x8 A1 = __builtin_bit_cast(bf16x8, *(const u16x8*)(wAc + aoff + 16 * 28 * 16 + s * 32));
            int tapB = tapA > 26 ? 26 : tapA;
            int dz = tapB / 9;
            int rr = tapB - dz * 9;
            int dy = rr / 3;
            int dx = rr - dy * 3;
            int zr = zw + dz;
#pragma unroll
            for (int yr = 0; yr < 2; ++yr) {
                int yy = 2 * yp + yr + dy;
                int eb = (((zr * 6 + yy) * 2 + ch) * 50 + ln + dx) * 8;
#pragma unroll
                for (int xt = 0; xt < 3; ++xt) {
                    bf16x8 Bf = __builtin_bit_cast(bf16x8, *(const u16x8*)&sx[eb + xt * 128]);
                    acc[yr][xt][0] = __builtin_amdgcn_mfma_f32_16x16x32_bf16(A0, Bf, acc[yr][xt][0], 0, 0, 0);
                    acc[yr][xt][1] = __builtin_amdgcn_mfma_f32_16x16x32_bf16(A1, Bf, acc[yr][xt][1], 0, 0, 0);
                }
            }
        }
    }

    int oz = z0 + zw;
    if (oz < 46) {
#pragma unroll
        for (int yr = 0; yr < 2; ++yr) {
            int oy = y0 + 2 * yp + yr;
            if (oy >= 46) continue;
#pragma unroll
            for (int xt = 0; xt < 3; ++xt) {
                int ox = xt * 16 + ln;
                if (ox >= 46) continue;
#pragma unroll
                for (int h = 0; h < 2; ++h) {
                    f32x4 a = acc[yr][xt][h];
#pragma unroll
                    for (int r = 0; r < 4; ++r) {
                        int co = h * 16 + rg * 4 + r;
                        out[(size_t)(b * 32 + co) * 97336 + oz * 2116 + oy * 46 + ox]
                            = a[r] + bias[co];
                    }
                }
            }
        }
    }
}

extern "C" void kernel_launch(void* const* d_in, const int* in_sizes, int n_in,
                              void* d_out, int out_size, void* d_ws, size_t ws_size,
                              hipStream_t stream) {
    const float* x    = (const float*)d_in[0];
    const float* s    = (const float*)d_in[1];
    const float* sw   = (const float*)d_in[2];
    const float* sb   = (const float*)d_in[3];
    const float* wgt  = (const float*)d_in[4];
    const float* bias = (const float*)d_in[5];
    float* out = (float*)d_out;

    const size_t need = (size_t)XT_BYTES + WA_ELEMS * sizeof(u16);
    if (ws_size >= need) {
        u16* xT = (u16*)d_ws;
        u16* wA = (u16*)((char*)d_ws + XT_BYTES);
        hipLaunchKernelGGL(xpose_kernel, dim3(3456), dim3(256), 0, stream, x, xT);
        hipLaunchKernelGGL(wnorm8_kernel, dim3(256), dim3(64), 0, stream,
                           s, sw, sb, wgt, wA);
        hipLaunchKernelGGL(conv_dma, dim3(12 * 12 * 8), dim3(512), 0, stream,
                           xT, wA, bias, out);
    } else {
        u16* wA = (u16*)d_ws;
        hipLaunchKernelGGL(wnorm16_kernel, dim3(256), dim3(64), 0, stream,
                           s, sw, sb, wgt, wA);
        hipLaunchKernelGGL(conv_fallback, dim3(12 * 12 * 8), dim3(512), 0, stream,
                           x, wA, bias, out);
    }
}